// Round 1
// 61.987 us; speedup vs baseline: 1.0405x; 1.0405x over previous
//
#include <hip/hip_runtime.h>
#include <math.h>

#define KS   35
#define PAD  17
#define H    128
#define W    128
#define TLX  16          // pixels per block, x
#define TLY  2           // pixels per block, y
#define TW   51          // tile width : qc(<=7)+sj(<=3)+4*10(=40) -> 50, +1
#define TH   41          // tile height: qy(<=1)+di(<=39) -> 40, +1
#define BLK  512

struct alignas(16) F4 { float c0, c1, c2, pd; };

__device__ __forceinline__ int reflect_idx(int p) {
    // jnp.pad mode='reflect'; max overhang 33 < H so one reflection suffices
    if (p < 0) p = -p;
    if (p >= H) p = 2 * H - 2 - p;
    return p;
}

__global__ __launch_bounds__(BLK, 4)   // 4 waves/EU -> 16 waves/CU (2 blocks), VGPR<=128
void bilateral_kernel(const float* __restrict__ x, float* __restrict__ out) {
    __shared__ F4 s_in[TH * TW];   // 2091 * 16 = 33456 B -> 2 blocks/CU = 66.9 KB

    const int tid = threadIdx.x;
    const int tx0 = blockIdx.x * TLX;
    const int ty0 = blockIdx.y * TLY;

    // sigma = 5.6 exactly; 2*sigma^2 = 62.72. log2-domain weights; the
    // wd- and G-normalizations cancel in out = sum(w p)/sum(w).
    const float LOG2E  = 1.4426950408889634f;
    const float c_sp   = LOG2E / 62.72f;           // spatial coeff
    const float c_rng  = LOG2E / (62.72f * 9.0f);  // range coeff, /9 folds mean's 1/3
    const float NEGBIG = -1.0e30f;                 // exp2 -> 0 : kills padded taps

    // stage tile: reflect resolved once, channels interleaved -> b128 reads.
    // 2091 entries / 512 threads = 4.1 iters; unrolled so all loads pipeline.
    #pragma unroll
    for (int it = 0; it < 5; ++it) {
        int idx = tid + it * BLK;
        if (idx < TH * TW) {
            int ly = idx / TW, lx = idx - ly * TW;
            int gy = reflect_idx(ty0 - PAD + ly);
            int gx = reflect_idx(tx0 - PAD + lx);
            F4 v;
            v.c0 = x[gy * W + gx];
            v.c1 = x[H * W + gy * W + gx];
            v.c2 = x[2 * H * W + gy * W + gx];
            v.pd = 0.0f;
            s_in[idx] = v;
        }
    }
    __syncthreads();

    // thread -> (quad, si, sj): 16 quads of 32 lanes; quad owns 2 pixels
    // (row qy, x = qc + 8p). Taps: di = si+8t (rows padded to 40),
    // dj = sj+4j (cols padded to 36). 32 lanes reduce per pixel pair.
    const int sub  = tid & 31;
    const int si   = sub >> 2;       // 0..7
    const int sj   = sub & 3;        // 0..3
    const int quad = tid >> 5;       // 0..15
    const int qy   = quad >> 3;      // 0..1
    const int qc   = quad & 7;       // 0..7

    // centers for the 2 pixels (pd dropped -> 6 regs)
    float c0[2], c1[2], c2[2];
    #pragma unroll
    for (int p = 0; p < 2; ++p) {
        F4 c = s_in[(qy + PAD) * TW + (qc + 8 * p + PAD)];
        c0[p] = c.c0; c1[p] = c.c1; c2[p] = c.c2;
    }

    // column log2-gaussian terms; dj=35 is padding -> -inf
    float b[9];
    #pragma unroll
    for (int j = 0; j < 9; ++j) {
        int dj = sj + 4 * j;
        float fd = (float)(dj - PAD);
        b[j] = (dj <= 34) ? (-c_sp * fd * fd) : NEGBIG;
    }

    float a0[2] = {0.f, 0.f};
    float a1[2] = {0.f, 0.f};
    float a2[2] = {0.f, 0.f};
    float ad[2] = {0.f, 0.f};

    #pragma unroll
    for (int t = 0; t < 5; ++t) {
        const int di = si + 8 * t;                 // <= 39 (35..39 padded)
        float fdi = (float)(di - PAD);
        float a = (di <= 34) ? (-c_sp * fdi * fdi) : NEGBIG;

        // tap col for (p,j) = (qc+sj) + 4*(2p+j)  ->  v[2p+j], 2p+j in 0..10
        const F4* row = &s_in[(qy + di) * TW + (qc + sj)];
        F4 v[11];
        #pragma unroll
        for (int k = 0; k < 11; ++k) v[k] = row[4 * k];

        float ab[9];
        #pragma unroll
        for (int j = 0; j < 9; ++j) ab[j] = a + b[j];

        #pragma unroll
        for (int p = 0; p < 2; ++p) {
            #pragma unroll
            for (int j = 0; j < 9; ++j) {
                F4 q = v[2 * p + j];               // read shared by both pixels
                float s = fabsf(q.c0 - c0[p]) + fabsf(q.c1 - c1[p])
                        + fabsf(q.c2 - c2[p]);
                float w = __builtin_amdgcn_exp2f(fmaf(s * s, -c_rng, ab[j]));
                a0[p] = fmaf(w, q.c0, a0[p]);
                a1[p] = fmaf(w, q.c1, a1[p]);
                a2[p] = fmaf(w, q.c2, a2[p]);
                ad[p] += w;
            }
        }
    }

    // reduce across the 32 sub-lanes (masks <32 stay inside each half-wave)
    #pragma unroll
    for (int m = 1; m <= 16; m <<= 1) {
        #pragma unroll
        for (int p = 0; p < 2; ++p) {
            a0[p] += __shfl_xor(a0[p], m);
            a1[p] += __shfl_xor(a1[p], m);
            a2[p] += __shfl_xor(a2[p], m);
            ad[p] += __shfl_xor(ad[p], m);
        }
    }

    if (sub == 0) {
        int gy = ty0 + qy;
        #pragma unroll
        for (int p = 0; p < 2; ++p) {
            int gx = tx0 + qc + 8 * p;
            float inv = 1.0f / ad[p];
            out[(0 * H + gy) * W + gx] = a0[p] * inv;
            out[(1 * H + gy) * W + gx] = a1[p] * inv;
            out[(2 * H + gy) * W + gx] = a2[p] * inv;
        }
    }
}

extern "C" void kernel_launch(void* const* d_in, const int* in_sizes, int n_in,
                              void* d_out, int out_size, void* d_ws, size_t ws_size,
                              hipStream_t stream) {
    const float* x = (const float*)d_in[0];
    float* out = (float*)d_out;
    dim3 grid(W / TLX, H / TLY);   // 8 x 64 = 512 blocks, 512 thr -> 16 waves/CU
    dim3 block(BLK);
    bilateral_kernel<<<grid, block, 0, stream>>>(x, out);
}